// Round 13
// baseline (19.885 us; speedup 1.0000x reference)
//
#include <hip/hip_runtime.h>
#include <math.h>

#define NATOMS 32
#define NMOL   64
#define MAXP   466     // >= C(31,2)=465
#define RCRf 5.2f
#define RCAf 3.5f

// One block per (molecule n, center atom i). 512 threads (8 waves), 3 barriers.
// A (wave 0): atom setup; compaction writes atom data BY COMPACT INDEX
//    (s_catom/s_cfs) so phase B needs no nbr indirection.
// radial (wave 7, tid>=448): runs BETWEEN barriers 1 and 2, overlapping B.
// B (tid<448, p=tid and rare p=tid+448): decode pair in compacted space,
//    build factorized record {f1[0..7], f2f[0..3]} in registers, histogram px.
// C: slot = in-register prefix + atomicAdd rank; 3x ds_write_b128.
// E: tid<320 owns angular feature (b=tid>>5, a, z), scans only bucket b.
__global__ __launch_bounds__(512) void aev_kernel(const int* __restrict__ species,
                                                  const float* __restrict__ coords,
                                                  float* __restrict__ out) {
    const int bid = blockIdx.x;
    const int n = bid >> 5;
    const int i = bid & 31;
    const int tid = threadIdx.x;

    __shared__ float4 s_catom[NATOMS];           // compacted: dx, dy, dz, d
    __shared__ float2 s_cfs[NATOMS];             // compacted: fca, species
    __shared__ float2 s_dfr[NATOMS];             // original idx: d, fcr (radial)
    __shared__ int    s_sp[NATOMS];
    __shared__ int    s_nn;
    __shared__ __align__(16) float s_rec[MAXP*12];   // f1[0..7], f2f[0..3]
    __shared__ int    s_cnt[10], s_rank[10];

    // ---------- phase A (wave 0) ----------
    if (tid < 10) { s_cnt[tid] = 0; s_rank[tid] = 0; }
    if (tid < 64) {
        float fca_v = 0.f, sv = 0.f;
        float4 av;
        if (tid < NATOMS) {
            const float* cb = coords + (size_t)n*NATOMS*3;
            float dx = cb[tid*3+0] - cb[i*3+0];
            float dy = cb[tid*3+1] - cb[i*3+1];
            float dz = cb[tid*3+2] - cb[i*3+2];
            float d2 = dx*dx + dy*dy + dz*dz;
            float d  = sqrtf(d2 > 0.f ? d2 : 1.f);   // ref's where(d2>0,d2,1) guard
            bool self = (tid == i);
            float fr = (!self && d <= RCRf) ? (0.5f*__cosf(((float)M_PI/RCRf)*d) + 0.5f) : 0.f;
            fca_v    = (!self && d <= RCAf) ? (0.5f*__cosf(((float)M_PI/RCAf)*d) + 0.5f) : 0.f;
            int spv = species[n*NATOMS + tid];
            s_dfr[tid] = make_float2(d, fr);
            s_sp[tid]  = spv;
            av = make_float4(dx, dy, dz, d);
            sv = (float)spv;
        }
        unsigned long long m = __ballot(fca_v > 0.f);  // full-wave-active context
        int ci = (int)__popcll(m & ((1ull << tid) - 1ull));
        if (fca_v > 0.f) { s_catom[ci] = av; s_cfs[ci] = make_float2(fca_v, sv); }
        if (tid == 0) s_nn = (int)__popcll(m);
    }
    __syncthreads();                                   // barrier 1

    const int nn  = s_nn;
    const int cnt = (nn*(nn-1)) >> 1;                  // <= 465
    const int M   = 2*nn - 1;
    float* oa = out + NMOL*NATOMS + (size_t)bid * 384;

    const float CZ[8] = { 0.98078528f,  0.83146961f,  0.55557023f,  0.19509032f,
                         -0.19509032f, -0.55557023f, -0.83146961f, -0.98078528f};
    const float SZ[8] = { 0.19509032f,  0.55557023f,  0.83146961f,  0.98078528f,
                          0.98078528f,  0.83146961f,  0.55557023f,  0.19509032f};
    const float SHA[4] = {0.9f, 1.55f, 2.2f, 2.85f};

    // ---------- radial (wave 7) -- overlaps phase B ----------
    if (tid >= 448) {
        const int f  = tid - 448;
        const int rs = f >> 4;
        const float shr = 0.9f + 0.26875f * (float)(f & 15);   // SHF_R
        float racc = 0.f;
        #pragma unroll 8
        for (int j = 0; j < NATOMS; ++j) {
            float2 dfr = s_dfr[j];                     // fr==0 encodes mask
            float dmr = dfr.x - shr;
            racc += (s_sp[j] == rs) ? 0.25f * __expf(-16.f*dmr*dmr) * dfr.y : 0.f;
        }
        oa[f] = racc;
        if (tid == 511) out[bid] = (float)s_sp[i];     // output 0: species
    }

    // ---------- phase B (tid<448): record build + histogram ----------
    #define BUILD(P, PX, V0, V1, V2)                                            \
    {                                                                           \
        float t = sqrtf((float)(M*M - 8*(P)));                                  \
        int jj = (int)(((float)M - t) * 0.5f);                                  \
        jj = max(0, min(jj, nn-2));                                             \
        while (jj*(2*nn-jj-1)/2 > (P)) --jj;                                    \
        while ((jj+1)*(2*nn-jj-2)/2 <= (P)) ++jj;                               \
        int kk = (P) - jj*(2*nn-jj-1)/2 + jj + 1;                               \
        float4 aj = s_catom[jj], ak = s_catom[kk];                              \
        float2 fj = s_cfs[jj],  fk = s_cfs[kk];                                 \
        float fc2 = 2.f * fj.x * fk.x;                                          \
        float dot = aj.x*ak.x + aj.y*ak.y + aj.z*ak.z;                          \
        float c = 0.95f * dot * __builtin_amdgcn_rcpf(aj.w * ak.w);             \
        c = fminf(0.95f, fmaxf(-0.95f, c));                                     \
        float s = sqrtf(1.f - c*c);                                             \
        float dmean = 0.5f * (aj.w + ak.w);                                     \
        int sj = (int)fj.y, sk = (int)fk.y;                                     \
        int lo = min(sj, sk), hi = max(sj, sk);                                 \
        PX = ((lo*(9-lo)) >> 1) + (hi - lo);                                    \
        V0.x = 0.5f + 0.5f*(c*CZ[0] + s*SZ[0]);                                 \
        V0.y = 0.5f + 0.5f*(c*CZ[1] + s*SZ[1]);                                 \
        V0.z = 0.5f + 0.5f*(c*CZ[2] + s*SZ[2]);                                 \
        V0.w = 0.5f + 0.5f*(c*CZ[3] + s*SZ[3]);                                 \
        V1.x = 0.5f + 0.5f*(c*CZ[4] + s*SZ[4]);                                 \
        V1.y = 0.5f + 0.5f*(c*CZ[5] + s*SZ[5]);                                 \
        V1.z = 0.5f + 0.5f*(c*CZ[6] + s*SZ[6]);                                 \
        V1.w = 0.5f + 0.5f*(c*CZ[7] + s*SZ[7]);                                 \
        V0.x*=V0.x; V0.x*=V0.x; V0.x*=V0.x; V0.x*=V0.x; V0.x*=V0.x;            \
        V0.y*=V0.y; V0.y*=V0.y; V0.y*=V0.y; V0.y*=V0.y; V0.y*=V0.y;            \
        V0.z*=V0.z; V0.z*=V0.z; V0.z*=V0.z; V0.z*=V0.z; V0.z*=V0.z;            \
        V0.w*=V0.w; V0.w*=V0.w; V0.w*=V0.w; V0.w*=V0.w; V0.w*=V0.w;            \
        V1.x*=V1.x; V1.x*=V1.x; V1.x*=V1.x; V1.x*=V1.x; V1.x*=V1.x;            \
        V1.y*=V1.y; V1.y*=V1.y; V1.y*=V1.y; V1.y*=V1.y; V1.y*=V1.y;            \
        V1.z*=V1.z; V1.z*=V1.z; V1.z*=V1.z; V1.z*=V1.z; V1.z*=V1.z;            \
        V1.w*=V1.w; V1.w*=V1.w; V1.w*=V1.w; V1.w*=V1.w; V1.w*=V1.w;            \
        float dm0 = dmean - SHA[0], dm1 = dmean - SHA[1];                       \
        float dm2 = dmean - SHA[2], dm3 = dmean - SHA[3];                       \
        V2.x = __expf(-8.f*dm0*dm0) * fc2;                                      \
        V2.y = __expf(-8.f*dm1*dm1) * fc2;                                      \
        V2.z = __expf(-8.f*dm2*dm2) * fc2;                                      \
        V2.w = __expf(-8.f*dm3*dm3) * fc2;                                      \
        atomicAdd(&s_cnt[PX], 1);                                               \
    }

    int pxA = -1, pxB = -1;
    float4 a0, a1, a2, b0, b1, b2;
    if (tid < 448) {
        if (tid < cnt) BUILD(tid, pxA, a0, a1, a2);
        int p2 = tid + 448;
        if (p2 < cnt) BUILD(p2, pxB, b0, b1, b2);      // only when cnt>448 (rare)
    }
    #undef BUILD
    __syncthreads();                                   // barrier 2

    int c0=0,c1=0,c2=0,c3=0,c4=0,c5=0,c6=0,c7=0,c8=0,c9=0;
    if (tid < 448) {
        c0 = s_cnt[0]; c1 = s_cnt[1]; c2 = s_cnt[2]; c3 = s_cnt[3]; c4 = s_cnt[4];
        c5 = s_cnt[5]; c6 = s_cnt[6]; c7 = s_cnt[7]; c8 = s_cnt[8]; c9 = s_cnt[9];
    }

    // ---------- phase C: slot = prefix + rank; write records ----------
    if (pxA >= 0) {
        int base = 0;
        base += (pxA > 0) ? c0 : 0;  base += (pxA > 1) ? c1 : 0;
        base += (pxA > 2) ? c2 : 0;  base += (pxA > 3) ? c3 : 0;
        base += (pxA > 4) ? c4 : 0;  base += (pxA > 5) ? c5 : 0;
        base += (pxA > 6) ? c6 : 0;  base += (pxA > 7) ? c7 : 0;
        base += (pxA > 8) ? c8 : 0;
        int slot = base + atomicAdd(&s_rank[pxA], 1);
        float* r = &s_rec[slot*12];
        *(float4*)(r+0) = a0; *(float4*)(r+4) = a1; *(float4*)(r+8) = a2;
    }
    if (pxB >= 0) {
        int base = 0;
        base += (pxB > 0) ? c0 : 0;  base += (pxB > 1) ? c1 : 0;
        base += (pxB > 2) ? c2 : 0;  base += (pxB > 3) ? c3 : 0;
        base += (pxB > 4) ? c4 : 0;  base += (pxB > 5) ? c5 : 0;
        base += (pxB > 6) ? c6 : 0;  base += (pxB > 7) ? c7 : 0;
        base += (pxB > 8) ? c8 : 0;
        int slot = base + atomicAdd(&s_rank[pxB], 1);
        float* r = &s_rec[slot*12];
        *(float4*)(r+0) = b0; *(float4*)(r+4) = b1; *(float4*)(r+8) = b2;
    }
    __syncthreads();                                   // barrier 3

    // ---------- phase E: angular feature ownership ----------
    if (tid < 320) {
        const int b = tid >> 5;
        const int a = (tid >> 3) & 3;
        const int z = tid & 7;
        int base = 0;
        base += (b > 0) ? c0 : 0;  base += (b > 1) ? c1 : 0;
        base += (b > 2) ? c2 : 0;  base += (b > 3) ? c3 : 0;
        base += (b > 4) ? c4 : 0;  base += (b > 5) ? c5 : 0;
        base += (b > 6) ? c6 : 0;  base += (b > 7) ? c7 : 0;
        base += (b > 8) ? c8 : 0;
        int bc = b==0?c0 : b==1?c1 : b==2?c2 : b==3?c3 : b==4?c4
               : b==5?c5 : b==6?c6 : b==7?c7 : b==8?c8 : c9;
        float acc = 0.f;
        #pragma unroll 4
        for (int q = base; q < base + bc; ++q)
            acc += s_rec[q*12 + z] * s_rec[q*12 + 8 + a];
        oa[64 + tid] = acc;
    }
}

extern "C" void kernel_launch(void* const* d_in, const int* in_sizes, int n_in,
                              void* d_out, int out_size, void* d_ws, size_t ws_size,
                              hipStream_t stream) {
    const int*   species = (const int*)d_in[0];
    const float* coords  = (const float*)d_in[1];
    float*       out     = (float*)d_out;
    aev_kernel<<<NMOL * NATOMS, 512, 0, stream>>>(species, coords, out);
}